// Round 7
// baseline (551.710 us; speedup 1.0000x reference)
//
#include <hip/hip_runtime.h>
#include <math.h>

// GCN 2-layer + sigmoid head. CSR pull-gather, zero fp32 atomics.
// Stage 1: bucket edges by dst (NB=256 nodes/bucket). k_fillbin LDS-sorts each
//          4096-edge chunk by bucket; final global address is computed AT
//          SCATTER TIME (gaddr array) -> flush is two stride-1 LDS reads +
//          coalesced run store. (R7: removes R6's divergent binary search.)
// Stage 2: per-bucket LDS counting sort -> csr[] sorted by dst, rowptr[], dinv[]
// Stage 3: wave-per-node gather (4 lanes/edge, line-coalesced), register acc,
//          shfl butterfly reduce, fused epilogue (norm+bias+relu+next GEMV).

#define TPB 256
#define NBS 8
#define NB 256          // nodes per bucket
#define MAXB 1024       // max buckets (n <= 262144)
#define BPT (MAXB / TPB)
#define CHUNK 4096      // edges per fillbin block

__global__ void k_zero_i32(int* __restrict__ p, int n) {
    int i = blockIdx.x * blockDim.x + threadIdx.x;
    if (i < n) p[i] = 0;
}

// global per-bucket edge counts via per-block LDS histograms
__global__ void k_hist(const int* __restrict__ dst, int* __restrict__ bc, int e, int nb) {
    __shared__ int h[MAXB];
    for (int t = threadIdx.x; t < nb; t += blockDim.x) h[t] = 0;
    __syncthreads();
    int stride = gridDim.x * blockDim.x;
    for (int i = blockIdx.x * blockDim.x + threadIdx.x; i < e; i += stride)
        atomicAdd(&h[dst[i] >> NBS], 1);
    __syncthreads();
    for (int t = threadIdx.x; t < nb; t += blockDim.x)
        if (h[t]) atomicAdd(&bc[t], h[t]);
}

// exclusive scan of bucket counts (nb <= 1024), single block of 1024
__global__ void k_scan(const int* __restrict__ bc, int* __restrict__ bbase,
                       int* __restrict__ gcur, int nb) {
    __shared__ int sm[MAXB];
    int t = threadIdx.x;
    int v = (t < nb) ? bc[t] : 0;
    sm[t] = v;
    __syncthreads();
    for (int off = 1; off < MAXB; off <<= 1) {
        int a = (t >= off) ? sm[t - off] : 0;
        __syncthreads();
        sm[t] += a;
        __syncthreads();
    }
    if (t < nb) { int ex = sm[t] - v; bbase[t] = ex; gcur[t] = ex; }
}

// bin edges into bucket regions. LDS counting sort of the chunk; global target
// address computed at scatter time; coalesced flush. word: ((d&255)<<18)|s
__global__ void __launch_bounds__(TPB) k_fillbin(
        const int* __restrict__ src, const int* __restrict__ dst,
        int* __restrict__ gcur, int* __restrict__ binned, int e, int nb) {
    __shared__ int stage[CHUNK];   // bucket-sorted packed words
    __shared__ int gaddr[CHUNK];   // global destination of each sorted slot
    __shared__ int h[MAXB];        // counts, then scatter cursors
    __shared__ int excl[MAXB];     // exclusive prefix within chunk
    __shared__ int delta[MAXB];    // global_base - excl
    __shared__ int tmp[TPB];
    int t = threadIdx.x;
    int c0 = blockIdx.x * CHUNK;
    int csize = min(e - c0, CHUNK);
#pragma unroll
    for (int k = 0; k < BPT; k++) h[t * BPT + k] = 0;
    __syncthreads();
    // 1) histogram
    for (int i = c0 + t; i < c0 + csize; i += TPB)
        atomicAdd(&h[dst[i] >> NBS], 1);
    __syncthreads();
    // 2) block-wide exclusive scan of h (BPT bins per thread)
    int loc[BPT];
    int ts = 0;
#pragma unroll
    for (int k = 0; k < BPT; k++) { loc[k] = ts; ts += h[t * BPT + k]; }
    tmp[t] = ts;
    __syncthreads();
    for (int off = 1; off < TPB; off <<= 1) {
        int a = (t >= off) ? tmp[t - off] : 0;
        __syncthreads();
        tmp[t] += a;
        __syncthreads();
    }
    int tbase = tmp[t] - ts;  // exclusive across threads
#pragma unroll
    for (int k = 0; k < BPT; k++) excl[t * BPT + k] = tbase + loc[k];
    __syncthreads();
    // 3) reserve global runs; delta maps chunk-local slot -> global slot
#pragma unroll
    for (int k = 0; k < BPT; k++) {
        int b = t * BPT + k;
        int cnt = h[b];
        int gb = cnt ? atomicAdd(&gcur[b], cnt) : 0;
        delta[b] = gb - excl[b];
    }
    __syncthreads();
#pragma unroll
    for (int k = 0; k < BPT; k++) { int b = t * BPT + k; h[b] = excl[b]; }
    __syncthreads();
    // 4) scatter into LDS stage; compute global address here (no search later)
    for (int i = c0 + t; i < c0 + csize; i += TPB) {
        int d = dst[i], s = src[i];
        int b = d >> NBS;
        int r = atomicAdd(&h[b], 1);
        stage[r] = ((d & (NB - 1)) << 18) | s;
        gaddr[r] = delta[b] + r;
    }
    __syncthreads();
    // 5) coalesced flush: stride-1 LDS reads, run-contiguous global stores
    for (int k = t; k < csize; k += TPB)
        binned[gaddr[k]] = stage[k];
}

// per-bucket counting sort by d_local -> csr (src ids sorted by dst), rowptr, dinv
__global__ void __launch_bounds__(NB) k_sort(
        const int* __restrict__ binned, const int* __restrict__ bbase,
        const int* __restrict__ bc, int* __restrict__ csr, int* __restrict__ rowptr,
        float* __restrict__ dinv, int n, int nb, int e) {
    __shared__ int cnt[NB];
    __shared__ int excl[NB];
    __shared__ int curs[NB];
    int b = blockIdx.x, t = threadIdx.x;
    cnt[t] = 0;
    __syncthreads();
    int base = bbase[b], c = bc[b];
    for (int j = base + t; j < base + c; j += NB)
        atomicAdd(&cnt[binned[j] >> 18], 1);
    __syncthreads();
    int v = cnt[t];
    excl[t] = v;
    __syncthreads();
    for (int off = 1; off < NB; off <<= 1) {
        int a = (t >= off) ? excl[t - off] : 0;
        __syncthreads();
        excl[t] += a;
        __syncthreads();
    }
    int ex = excl[t] - v;  // exclusive prefix within bucket
    curs[t] = ex;
    int i = (b << NBS) + t;
    rowptr[i] = base + ex;
    if (i < n) dinv[i] = rsqrtf((float)(v + 1));
    if (b == nb - 1 && t == 0) rowptr[nb << NBS] = e;
    __syncthreads();
    for (int j = base + t; j < base + c; j += NB) {
        int p = binned[j];
        int pos = base + atomicAdd(&curs[p >> 18], 1);
        csr[pos] = p & 0x3FFFF;
    }
}

// g1[i] = (x[i] @ W1) * dinv[i]
__global__ void k_g1(const float* __restrict__ x, const float* __restrict__ W1,
                     const float* __restrict__ dinv, float* __restrict__ g1, int n) {
    __shared__ float w[96];  // 6 x 16
    if (threadIdx.x < 96) w[threadIdx.x] = W1[threadIdx.x];
    __syncthreads();
    int i = blockIdx.x * blockDim.x + threadIdx.x;
    if (i >= n) return;
    float xv[6];
#pragma unroll
    for (int k = 0; k < 6; k++) xv[k] = x[i * 6 + k];
    float di = dinv[i];
    float4* out = (float4*)g1;
#pragma unroll
    for (int q = 0; q < 4; q++) {
        float4 o;
        float* op = (float*)&o;
#pragma unroll
        for (int r = 0; r < 4; r++) {
            int f = q * 4 + r;
            float h = 0.0f;
#pragma unroll
            for (int k = 0; k < 6; k++) h += xv[k] * w[k * 16 + f];
            op[r] = h * di;
        }
        out[i * 4 + q] = o;
    }
}

// layer-1 gather: wave per node, 4 lanes/edge (quad=neighbor slot, fq=feature quad)
// fused epilogue: t = relu(dinv*(acc+self)+b1); g2 = (t @ W2) * dinv
__global__ void __launch_bounds__(TPB) k_gat1(
        const float* __restrict__ g1, const int* __restrict__ csr,
        const int* __restrict__ rowptr, const float* __restrict__ dinv,
        const float* __restrict__ b1, const float* __restrict__ W2,
        float* __restrict__ g2, int n) {
    __shared__ float w[128];   // 16 x 8
    __shared__ float bb[16];
    __shared__ float tsh[4][16];
    if (threadIdx.x < 128) w[threadIdx.x] = W2[threadIdx.x];
    if (threadIdx.x < 16) bb[threadIdx.x] = b1[threadIdx.x];
    __syncthreads();
    int wv = threadIdx.x >> 6;
    int lane = threadIdx.x & 63;
    int quad = lane >> 2, fq = lane & 3;
    int i = blockIdx.x * 4 + wv;
    bool valid = (i < n);
    int r0 = 0, r1 = 0;
    if (valid) { r0 = rowptr[i]; r1 = rowptr[i + 1]; }
    const float4* gv = (const float4*)g1;
    float4 a0 = make_float4(0.f, 0.f, 0.f, 0.f);
    float4 a1 = make_float4(0.f, 0.f, 0.f, 0.f);
    int j = r0 + quad;
    while (j + 16 < r1) {  // per-lane bound: each lane covers its slots exactly once
        int s0 = csr[j], s1 = csr[j + 16];
        float4 x0 = gv[s0 * 4 + fq];
        float4 x1 = gv[s1 * 4 + fq];
        a0.x += x0.x; a0.y += x0.y; a0.z += x0.z; a0.w += x0.w;
        a1.x += x1.x; a1.y += x1.y; a1.z += x1.z; a1.w += x1.w;
        j += 32;
    }
    if (j < r1) {
        int s0 = csr[j];
        float4 x0 = gv[s0 * 4 + fq];
        a0.x += x0.x; a0.y += x0.y; a0.z += x0.z; a0.w += x0.w;
    }
    float4 acc = make_float4(a0.x + a1.x, a0.y + a1.y, a0.z + a1.z, a0.w + a1.w);
#pragma unroll
    for (int m = 4; m <= 32; m <<= 1) {  // reduce across 16 neighbor-slot lanes
        acc.x += __shfl_xor(acc.x, m);
        acc.y += __shfl_xor(acc.y, m);
        acc.z += __shfl_xor(acc.z, m);
        acc.w += __shfl_xor(acc.w, m);
    }
    if (valid && quad == 0) {
        float di = dinv[i];
        float4 s = gv[i * 4 + fq];  // self-loop term
        float4 tq;
        tq.x = fmaxf(di * (acc.x + s.x) + bb[fq * 4 + 0], 0.0f);
        tq.y = fmaxf(di * (acc.y + s.y) + bb[fq * 4 + 1], 0.0f);
        tq.z = fmaxf(di * (acc.z + s.z) + bb[fq * 4 + 2], 0.0f);
        tq.w = fmaxf(di * (acc.w + s.w) + bb[fq * 4 + 3], 0.0f);
        ((float4*)tsh[wv])[fq] = tq;
    }
    __syncthreads();
    if (valid && quad == 0) {
        float di = dinv[i];
        float h0 = 0.0f, h1 = 0.0f;
#pragma unroll
        for (int f = 0; f < 16; f++) {
            float tv = tsh[wv][f];
            h0 += tv * w[f * 8 + fq * 2 + 0];
            h1 += tv * w[f * 8 + fq * 2 + 1];
        }
        ((float2*)g2)[i * 4 + fq] = make_float2(h0 * di, h1 * di);
    }
}

// layer-2 gather: wave per node, 2 lanes/edge (half=slot, fh=feature half)
// fused head: h = relu(dinv*(acc+self)+b2); out = sigmoid(h @ Wfc + bfc)
__global__ void __launch_bounds__(TPB) k_gat2(
        const float* __restrict__ g2, const int* __restrict__ csr,
        const int* __restrict__ rowptr, const float* __restrict__ dinv,
        const float* __restrict__ b2, const float* __restrict__ Wfc,
        const float* __restrict__ bfc, float* __restrict__ out, int n) {
    __shared__ float w[8];
    __shared__ float bb[8];
    __shared__ float bf;
    if (threadIdx.x < 8) { w[threadIdx.x] = Wfc[threadIdx.x]; bb[threadIdx.x] = b2[threadIdx.x]; }
    if (threadIdx.x == 0) bf = bfc[0];
    __syncthreads();
    int wv = threadIdx.x >> 6;
    int lane = threadIdx.x & 63;
    int half = lane >> 1, fh = lane & 1;
    int i = blockIdx.x * 4 + wv;
    bool valid = (i < n);
    int r0 = 0, r1 = 0;
    if (valid) { r0 = rowptr[i]; r1 = rowptr[i + 1]; }
    const float4* gv = (const float4*)g2;
    float4 acc = make_float4(0.f, 0.f, 0.f, 0.f);
    for (int j = r0 + half; j < r1; j += 32) {
        int s0 = csr[j];
        float4 x0 = gv[s0 * 2 + fh];
        acc.x += x0.x; acc.y += x0.y; acc.z += x0.z; acc.w += x0.w;
    }
#pragma unroll
    for (int m = 2; m <= 32; m <<= 1) {  // reduce across 32 neighbor-slot lanes
        acc.x += __shfl_xor(acc.x, m);
        acc.y += __shfl_xor(acc.y, m);
        acc.z += __shfl_xor(acc.z, m);
        acc.w += __shfl_xor(acc.w, m);
    }
    if (valid && half == 0) {  // lanes 0,1 both active -> shfl_xor(…,1) safe
        float di = dinv[i];
        float4 s = gv[i * 2 + fh];
        float o4 = 0.0f;
        o4 += fmaxf(di * (acc.x + s.x) + bb[fh * 4 + 0], 0.0f) * w[fh * 4 + 0];
        o4 += fmaxf(di * (acc.y + s.y) + bb[fh * 4 + 1], 0.0f) * w[fh * 4 + 1];
        o4 += fmaxf(di * (acc.z + s.z) + bb[fh * 4 + 2], 0.0f) * w[fh * 4 + 2];
        o4 += fmaxf(di * (acc.w + s.w) + bb[fh * 4 + 3], 0.0f) * w[fh * 4 + 3];
        float oo = o4 + __shfl_xor(o4, 1);
        if (fh == 0) out[i] = 1.0f / (1.0f + expf(-(oo + bf)));
    }
}

extern "C" void kernel_launch(void* const* d_in, const int* in_sizes, int n_in,
                              void* d_out, int out_size, void* d_ws, size_t ws_size,
                              hipStream_t stream) {
    const float* x   = (const float*)d_in[0];
    const int*   ei  = (const int*)d_in[1];
    const float* W1  = (const float*)d_in[2];
    const float* b1  = (const float*)d_in[3];
    const float* W2  = (const float*)d_in[4];
    const float* b2  = (const float*)d_in[5];
    const float* Wfc = (const float*)d_in[6];
    const float* bfc = (const float*)d_in[7];
    float* out = (float*)d_out;

    const int n = in_sizes[0] / 6;   // 200000 (<= 262144 for 18-bit packing)
    const int e = in_sizes[1] / 2;   // 6400000
    const int* src = ei;
    const int* dst = ei + e;
    const int nb = (n + NB - 1) >> NBS;   // 782
    const size_t np = (size_t)nb << NBS;  // padded node count (200192)

    int* bc     = (int*)d_ws;            // MAXB
    int* bbase  = bc + MAXB;             // MAXB
    int* gcur   = bbase + MAXB;          // MAXB
    int* binned = gcur + MAXB;           // e
    int* csr    = binned + e;            // e
    int* rowptr = csr + e;               // np + 4
    float* dinv = (float*)(rowptr + np + 4);  // np
    float* g1   = dinv + np;             // 16 np
    float* g2   = g1 + 16 * np;          // 8 np

    int gn = (n + TPB - 1) / TPB;
    int nblk = (e + CHUNK - 1) / CHUNK;  // 1563
    int gw = (n + 3) / 4;                // wave-per-node blocks (4 waves/block)

    k_zero_i32<<<1, MAXB, 0, stream>>>(bc, MAXB);
    k_hist<<<512, TPB, 0, stream>>>(dst, bc, e, nb);
    k_scan<<<1, MAXB, 0, stream>>>(bc, bbase, gcur, nb);
    k_fillbin<<<nblk, TPB, 0, stream>>>(src, dst, gcur, binned, e, nb);
    k_sort<<<nb, NB, 0, stream>>>(binned, bbase, bc, csr, rowptr, dinv, n, nb, e);
    k_g1<<<gn, TPB, 0, stream>>>(x, W1, dinv, g1, n);
    k_gat1<<<gw, TPB, 0, stream>>>(g1, csr, rowptr, dinv, b1, W2, g2, n);
    k_gat2<<<gw, TPB, 0, stream>>>(g2, csr, rowptr, dinv, b2, Wfc, bfc, out, n);
}

// Round 8
// 497.493 us; speedup vs baseline: 1.1090x; 1.1090x over previous
//
#include <hip/hip_runtime.h>
#include <math.h>

// GCN 2-layer + sigmoid head. CSR pull-gather, zero fp32 atomics.
// R8: layer-1 aggregation in PRE-W1 domain (xd = x*dinv, 6-dim padded to 8):
//     agg_h = (sum xd)@W1 by linearity -> gather reads 32B/edge instead of 64B.
//     Whole layer-1 node chain (agg@W1 -> relu -> @W2 -> *dinv) fused into
//     k_gat1 epilogue via shfl broadcast. 512-node buckets for fillbin/sort.
// Stage 1: bucket edges by dst (512 nodes/bucket), LDS chunk sort + coalesced flush
// Stage 2: per-bucket counting sort (512 thr) -> csr sorted by dst, rowptr, dinv
// Stage 3: wave-per-node gathers (2 lanes/edge), shfl reduce, fused epilogues.

#define TPB 256
#define NBS 9
#define NBKT 512        // nodes per bucket
#define MAXB 512        // max buckets (n <= 262144)
#define BPT (MAXB / TPB)
#define CHUNK 4096      // edges per fillbin block
#define STPB 512        // k_sort block size

__global__ void k_zero_i32(int* __restrict__ p, int n) {
    int i = blockIdx.x * blockDim.x + threadIdx.x;
    if (i < n) p[i] = 0;
}

// global per-bucket edge counts via per-block LDS histograms
__global__ void k_hist(const int* __restrict__ dst, int* __restrict__ bc, int e, int nb) {
    __shared__ int h[MAXB];
    for (int t = threadIdx.x; t < nb; t += blockDim.x) h[t] = 0;
    __syncthreads();
    int stride = gridDim.x * blockDim.x;
    for (int i = blockIdx.x * blockDim.x + threadIdx.x; i < e; i += stride)
        atomicAdd(&h[dst[i] >> NBS], 1);
    __syncthreads();
    for (int t = threadIdx.x; t < nb; t += blockDim.x)
        if (h[t]) atomicAdd(&bc[t], h[t]);
}

// exclusive scan of bucket counts (nb <= 512), single block of 512
__global__ void k_scan(const int* __restrict__ bc, int* __restrict__ bbase,
                       int* __restrict__ gcur, int nb) {
    __shared__ int sm[MAXB];
    int t = threadIdx.x;
    int v = (t < nb) ? bc[t] : 0;
    sm[t] = v;
    __syncthreads();
    for (int off = 1; off < MAXB; off <<= 1) {
        int a = (t >= off) ? sm[t - off] : 0;
        __syncthreads();
        sm[t] += a;
        __syncthreads();
    }
    if (t < nb) { int ex = sm[t] - v; bbase[t] = ex; gcur[t] = ex; }
}

// bin edges into bucket regions. LDS counting sort of the chunk; global target
// address computed at scatter time; coalesced flush. word: ((d&511)<<18)|s
__global__ void __launch_bounds__(TPB) k_fillbin(
        const int* __restrict__ src, const int* __restrict__ dst,
        int* __restrict__ gcur, int* __restrict__ binned, int e, int nb) {
    __shared__ int stage[CHUNK];   // bucket-sorted packed words
    __shared__ int gaddr[CHUNK];   // global destination of each sorted slot
    __shared__ int h[MAXB];        // counts, then scatter cursors
    __shared__ int excl[MAXB];     // exclusive prefix within chunk
    __shared__ int delta[MAXB];    // global_base - excl
    __shared__ int tmp[TPB];
    int t = threadIdx.x;
    int c0 = blockIdx.x * CHUNK;
    int csize = min(e - c0, CHUNK);
#pragma unroll
    for (int k = 0; k < BPT; k++) h[t * BPT + k] = 0;
    __syncthreads();
    // 1) histogram
    for (int i = c0 + t; i < c0 + csize; i += TPB)
        atomicAdd(&h[dst[i] >> NBS], 1);
    __syncthreads();
    // 2) block-wide exclusive scan of h (BPT bins per thread)
    int loc[BPT];
    int ts = 0;
#pragma unroll
    for (int k = 0; k < BPT; k++) { loc[k] = ts; ts += h[t * BPT + k]; }
    tmp[t] = ts;
    __syncthreads();
    for (int off = 1; off < TPB; off <<= 1) {
        int a = (t >= off) ? tmp[t - off] : 0;
        __syncthreads();
        tmp[t] += a;
        __syncthreads();
    }
    int tbase = tmp[t] - ts;  // exclusive across threads
#pragma unroll
    for (int k = 0; k < BPT; k++) excl[t * BPT + k] = tbase + loc[k];
    __syncthreads();
    // 3) reserve global runs; delta maps chunk-local slot -> global slot
#pragma unroll
    for (int k = 0; k < BPT; k++) {
        int b = t * BPT + k;
        int cnt = h[b];
        int gb = cnt ? atomicAdd(&gcur[b], cnt) : 0;
        delta[b] = gb - excl[b];
    }
    __syncthreads();
#pragma unroll
    for (int k = 0; k < BPT; k++) { int b = t * BPT + k; h[b] = excl[b]; }
    __syncthreads();
    // 4) scatter into LDS stage; compute global address here
    for (int i = c0 + t; i < c0 + csize; i += TPB) {
        int d = dst[i], s = src[i];
        int b = d >> NBS;
        int r = atomicAdd(&h[b], 1);
        stage[r] = ((d & (NBKT - 1)) << 18) | s;
        gaddr[r] = delta[b] + r;
    }
    __syncthreads();
    // 5) coalesced flush: stride-1 LDS reads, run-contiguous global stores
    for (int k = t; k < csize; k += TPB)
        binned[gaddr[k]] = stage[k];
}

// per-bucket counting sort by d_local -> csr (src ids sorted by dst), rowptr, dinv
__global__ void __launch_bounds__(STPB) k_sort(
        const int* __restrict__ binned, const int* __restrict__ bbase,
        const int* __restrict__ bc, int* __restrict__ csr, int* __restrict__ rowptr,
        float* __restrict__ dinv, int n, int nb, int e) {
    __shared__ int cnt[NBKT];
    __shared__ int excl[NBKT];
    __shared__ int curs[NBKT];
    int b = blockIdx.x, t = threadIdx.x;
    cnt[t] = 0;
    __syncthreads();
    int base = bbase[b], c = bc[b];
    for (int j = base + t; j < base + c; j += STPB)
        atomicAdd(&cnt[binned[j] >> 18], 1);
    __syncthreads();
    int v = cnt[t];
    excl[t] = v;
    __syncthreads();
    for (int off = 1; off < NBKT; off <<= 1) {
        int a = (t >= off) ? excl[t - off] : 0;
        __syncthreads();
        excl[t] += a;
        __syncthreads();
    }
    int ex = excl[t] - v;  // exclusive prefix within bucket
    curs[t] = ex;
    int i = (b << NBS) + t;
    rowptr[i] = base + ex;
    if (i < n) dinv[i] = rsqrtf((float)(v + 1));
    if (b == nb - 1 && t == 0) rowptr[nb << NBS] = e;
    __syncthreads();
    for (int j = base + t; j < base + c; j += STPB) {
        int p = binned[j];
        int pos = base + atomicAdd(&curs[p >> 18], 1);
        csr[pos] = p & 0x3FFFF;
    }
}

// xd8[i] = x[i]*dinv[i], 6 floats padded to 8 (two float4)
__global__ void k_xd(const float* __restrict__ x, const float* __restrict__ dinv,
                     float* __restrict__ xd8, int n) {
    int i = blockIdx.x * blockDim.x + threadIdx.x;
    if (i >= n) return;
    float di = dinv[i];
    float4* o = (float4*)xd8;
    o[i * 2 + 0] = make_float4(x[i * 6 + 0] * di, x[i * 6 + 1] * di,
                               x[i * 6 + 2] * di, x[i * 6 + 3] * di);
    o[i * 2 + 1] = make_float4(x[i * 6 + 4] * di, x[i * 6 + 5] * di, 0.f, 0.f);
}

// layer-1 gather in pre-W1 domain: wave per node, 2 lanes/edge (32B line halves)
// epilogue: agg6 (incl self) -> @W1 -> relu(di*.+b1) -> @W2 -> *di -> g2
__global__ void __launch_bounds__(TPB) k_gat1(
        const float* __restrict__ xd8, const int* __restrict__ csr,
        const int* __restrict__ rowptr, const float* __restrict__ dinv,
        const float* __restrict__ b1, const float* __restrict__ W1,
        const float* __restrict__ W2, float* __restrict__ g2, int n) {
    __shared__ float w1[96];   // 6 x 16
    __shared__ float w2[128];  // 16 x 8
    __shared__ float bb[16];
    if (threadIdx.x < 96) w1[threadIdx.x] = W1[threadIdx.x];
    if (threadIdx.x < 128) w2[threadIdx.x] = W2[threadIdx.x];
    if (threadIdx.x < 16) bb[threadIdx.x] = b1[threadIdx.x];
    __syncthreads();
    int wv = threadIdx.x >> 6, lane = threadIdx.x & 63;
    int slot = lane >> 1, fh = lane & 1;
    int i = blockIdx.x * 4 + wv;
    bool valid = (i < n);
    int r0 = 0, r1 = 0;
    if (valid) { r0 = rowptr[i]; r1 = rowptr[i + 1]; }
    const float4* gv = (const float4*)xd8;
    float4 a = make_float4(0.f, 0.f, 0.f, 0.f);
    float4 a2 = make_float4(0.f, 0.f, 0.f, 0.f);
    if (valid && lane < 2) a = gv[i * 2 + fh];  // self-loop term
    int j = r0 + slot;
    while (j + 32 < r1) {
        int s0 = csr[j], s1 = csr[j + 32];
        float4 x0 = gv[s0 * 2 + fh];
        float4 x1 = gv[s1 * 2 + fh];
        a.x += x0.x; a.y += x0.y; a.z += x0.z; a.w += x0.w;
        a2.x += x1.x; a2.y += x1.y; a2.z += x1.z; a2.w += x1.w;
        j += 64;
    }
    if (j < r1) {
        int s0 = csr[j];
        float4 x0 = gv[s0 * 2 + fh];
        a.x += x0.x; a.y += x0.y; a.z += x0.z; a.w += x0.w;
    }
    a.x += a2.x; a.y += a2.y; a.z += a2.z; a.w += a2.w;
#pragma unroll
    for (int m = 2; m <= 32; m <<= 1) {  // reduce across 32 slot lanes
        a.x += __shfl_xor(a.x, m);
        a.y += __shfl_xor(a.y, m);
        a.z += __shfl_xor(a.z, m);
        a.w += __shfl_xor(a.w, m);
    }
    // broadcast agg6 to all lanes (lane0 holds k=0..3, lane1 holds k=4..5)
    float a0 = __shfl(a.x, 0), a1 = __shfl(a.y, 0), a2b = __shfl(a.z, 0), a3 = __shfl(a.w, 0);
    float a4 = __shfl(a.x, 1), a5 = __shfl(a.y, 1);
    if (!valid) return;  // whole wave shares i -> uniform exit
    float di = dinv[i];
    int f = lane & 15;  // 4 redundant groups of 16 lanes compute t[f]
    float hf = a0 * w1[0 * 16 + f] + a1 * w1[1 * 16 + f] + a2b * w1[2 * 16 + f]
             + a3 * w1[3 * 16 + f] + a4 * w1[4 * 16 + f] + a5 * w1[5 * 16 + f];
    float tf = fmaxf(di * hf + bb[f], 0.0f);
    float p0 = tf * w2[f * 8 + 0], p1 = tf * w2[f * 8 + 1];
    float p2 = tf * w2[f * 8 + 2], p3 = tf * w2[f * 8 + 3];
    float p4 = tf * w2[f * 8 + 4], p5 = tf * w2[f * 8 + 5];
    float p6 = tf * w2[f * 8 + 6], p7 = tf * w2[f * 8 + 7];
#pragma unroll
    for (int m = 1; m <= 8; m <<= 1) {  // reduce over the 16 f-lanes
        p0 += __shfl_xor(p0, m); p1 += __shfl_xor(p1, m);
        p2 += __shfl_xor(p2, m); p3 += __shfl_xor(p3, m);
        p4 += __shfl_xor(p4, m); p5 += __shfl_xor(p5, m);
        p6 += __shfl_xor(p6, m); p7 += __shfl_xor(p7, m);
    }
    if (lane < 2) {
        float4 o = fh ? make_float4(p4, p5, p6, p7) : make_float4(p0, p1, p2, p3);
        o.x *= di; o.y *= di; o.z *= di; o.w *= di;
        ((float4*)g2)[i * 2 + fh] = o;
    }
}

// layer-2 gather: wave per node, 2 lanes/edge
// fused head: h = relu(dinv*(acc+self)+b2); out = sigmoid(h @ Wfc + bfc)
__global__ void __launch_bounds__(TPB) k_gat2(
        const float* __restrict__ g2, const int* __restrict__ csr,
        const int* __restrict__ rowptr, const float* __restrict__ dinv,
        const float* __restrict__ b2, const float* __restrict__ Wfc,
        const float* __restrict__ bfc, float* __restrict__ out, int n) {
    __shared__ float w[8];
    __shared__ float bb[8];
    __shared__ float bf;
    if (threadIdx.x < 8) { w[threadIdx.x] = Wfc[threadIdx.x]; bb[threadIdx.x] = b2[threadIdx.x]; }
    if (threadIdx.x == 0) bf = bfc[0];
    __syncthreads();
    int wv = threadIdx.x >> 6;
    int lane = threadIdx.x & 63;
    int half = lane >> 1, fh = lane & 1;
    int i = blockIdx.x * 4 + wv;
    bool valid = (i < n);
    int r0 = 0, r1 = 0;
    if (valid) { r0 = rowptr[i]; r1 = rowptr[i + 1]; }
    const float4* gv = (const float4*)g2;
    float4 acc = make_float4(0.f, 0.f, 0.f, 0.f);
    float4 acc2 = make_float4(0.f, 0.f, 0.f, 0.f);
    int j = r0 + half;
    while (j + 32 < r1) {
        int s0 = csr[j], s1 = csr[j + 32];
        float4 x0 = gv[s0 * 2 + fh];
        float4 x1 = gv[s1 * 2 + fh];
        acc.x += x0.x; acc.y += x0.y; acc.z += x0.z; acc.w += x0.w;
        acc2.x += x1.x; acc2.y += x1.y; acc2.z += x1.z; acc2.w += x1.w;
        j += 64;
    }
    if (j < r1) {
        int s0 = csr[j];
        float4 x0 = gv[s0 * 2 + fh];
        acc.x += x0.x; acc.y += x0.y; acc.z += x0.z; acc.w += x0.w;
    }
    acc.x += acc2.x; acc.y += acc2.y; acc.z += acc2.z; acc.w += acc2.w;
#pragma unroll
    for (int m = 2; m <= 32; m <<= 1) {  // reduce across 32 slot lanes
        acc.x += __shfl_xor(acc.x, m);
        acc.y += __shfl_xor(acc.y, m);
        acc.z += __shfl_xor(acc.z, m);
        acc.w += __shfl_xor(acc.w, m);
    }
    if (valid && half == 0) {  // lanes 0,1 both active -> shfl_xor(…,1) safe
        float di = dinv[i];
        float4 s = gv[i * 2 + fh];
        float o4 = 0.0f;
        o4 += fmaxf(di * (acc.x + s.x) + bb[fh * 4 + 0], 0.0f) * w[fh * 4 + 0];
        o4 += fmaxf(di * (acc.y + s.y) + bb[fh * 4 + 1], 0.0f) * w[fh * 4 + 1];
        o4 += fmaxf(di * (acc.z + s.z) + bb[fh * 4 + 2], 0.0f) * w[fh * 4 + 2];
        o4 += fmaxf(di * (acc.w + s.w) + bb[fh * 4 + 3], 0.0f) * w[fh * 4 + 3];
        float oo = o4 + __shfl_xor(o4, 1);
        if (fh == 0) out[i] = 1.0f / (1.0f + expf(-(oo + bf)));
    }
}

extern "C" void kernel_launch(void* const* d_in, const int* in_sizes, int n_in,
                              void* d_out, int out_size, void* d_ws, size_t ws_size,
                              hipStream_t stream) {
    const float* x   = (const float*)d_in[0];
    const int*   ei  = (const int*)d_in[1];
    const float* W1  = (const float*)d_in[2];
    const float* b1  = (const float*)d_in[3];
    const float* W2  = (const float*)d_in[4];
    const float* b2  = (const float*)d_in[5];
    const float* Wfc = (const float*)d_in[6];
    const float* bfc = (const float*)d_in[7];
    float* out = (float*)d_out;

    const int n = in_sizes[0] / 6;   // 200000 (<= 262144 for 18-bit packing)
    const int e = in_sizes[1] / 2;   // 6400000
    const int* src = ei;
    const int* dst = ei + e;
    const int nb = (n + NBKT - 1) >> NBS;  // 391
    const size_t np = (size_t)nb << NBS;   // padded node count (200192)

    int* bc     = (int*)d_ws;            // MAXB
    int* bbase  = bc + MAXB;             // MAXB
    int* gcur   = bbase + MAXB;          // MAXB
    int* binned = gcur + MAXB;           // e
    int* csr    = binned + e;            // e
    int* rowptr = csr + e;               // np + 4
    float* dinv = (float*)(rowptr + np + 4);  // np
    float* xd8  = dinv + np;             // 8 np
    float* g2   = xd8 + 8 * np;          // 8 np

    int gn = (n + TPB - 1) / TPB;
    int nblk = (e + CHUNK - 1) / CHUNK;  // 1563
    int gw = (n + 3) / 4;                // wave-per-node blocks (4 waves/block)

    k_zero_i32<<<1, MAXB, 0, stream>>>(bc, MAXB);
    k_hist<<<512, TPB, 0, stream>>>(dst, bc, e, nb);
    k_scan<<<1, MAXB, 0, stream>>>(bc, bbase, gcur, nb);
    k_fillbin<<<nblk, TPB, 0, stream>>>(src, dst, gcur, binned, e, nb);
    k_sort<<<nb, STPB, 0, stream>>>(binned, bbase, bc, csr, rowptr, dinv, n, nb, e);
    k_xd<<<gn, TPB, 0, stream>>>(x, dinv, xd8, n);
    k_gat1<<<gw, TPB, 0, stream>>>(xd8, csr, rowptr, dinv, b1, W1, W2, g2, n);
    k_gat2<<<gw, TPB, 0, stream>>>(g2, csr, rowptr, dinv, b2, Wfc, bfc, out, n);
}